// Round 15
// baseline (169.800 us; speedup 1.0000x reference)
//
#include <hip/hip_runtime.h>
#include <hip/hip_fp16.h>

#define BS 2
#define NS 50000
#define CCH 32
#define RR 128
#define SS 8

typedef float v2f __attribute__((ext_vector_type(2)));
typedef _Float16 h2 __attribute__((ext_vector_type(2)));

#if __has_builtin(__builtin_amdgcn_fdot2)
#define HAVE_DOT2 1
#else
#define HAVE_DOT2 0
#endif

// ws layout:
//   tp : BS*3*RR*RR blocks of 128 B (pair-replicated fp16 planes):
//        block (b,pl,y,x) holds channels c=0..31 interleaved {col x, col x+1}:
//        uint32 #c = half(src[c][y][x]) | half(src[c][y][min(x+1,127)])<<16
//        = 12,582,912 B
//   Wc : 1024 floats  (W_v @ W_out)
//   bvw: 32 floats    (b_v @ W_out)

// blocks 0..767: transpose+convert+replicate one (b,pl,y) row via LDS.
// blocks 768..771: compute Wc = Wv@Wout and bvw = bv@Wout.
__global__ __launch_bounds__(256)
void prep(const float* __restrict__ cxz,
          const float* __restrict__ cxy,
          const float* __restrict__ cyz,
          const float* __restrict__ Wv, const float* __restrict__ bv,
          const float* __restrict__ Wout,
          unsigned* __restrict__ tp, float* __restrict__ Wc,
          float* __restrict__ bvw) {
    __shared__ float lds[32 * 129];
    int tid = threadIdx.x;
    int row = blockIdx.x;
    if (row < BS * 3 * RR) {
        int y  = row & 127;
        int pl = (row >> 7) % 3;
        int b  = row / 384;
        const float* src = (pl == 0) ? cxz : ((pl == 1) ? cxy : cyz);
        const float* sp = src + (((size_t)(b * CCH)) << 14) + (y << 7);
#pragma unroll
        for (int i = 0; i < 16; ++i) {
            int c = (tid >> 7) + 2 * i;
            int x = tid & 127;
            lds[c * 129 + x] = sp[((size_t)c << 14) + x];
        }
        __syncthreads();
        unsigned* dst = tp + ((size_t)row << 12);   // 128 x * 32 c uints per row
#pragma unroll
        for (int i = 0; i < 16; ++i) {
            int idx = tid + 256 * i;                // 0..4095
            int c = idx & 31;
            int x = idx >> 5;
            int x1 = min(x + 1, 127);
            unsigned h0 = __half_as_ushort(__float2half(lds[c * 129 + x]));
            unsigned h1 = __half_as_ushort(__float2half(lds[c * 129 + x1]));
            dst[(x << 5) + c] = h0 | (h1 << 16);
        }
    } else {
        int t = (row - BS * 3 * RR) * 256 + tid;    // 0..1023
        int c = t >> 5, j = t & 31;
        float acc = 0.f;
#pragma unroll
        for (int k = 0; k < 32; ++k) acc += Wv[c * 32 + k] * Wout[k * 32 + j];
        Wc[t] = acc;
        if (t < 32) {
            float a2 = 0.f;
#pragma unroll
            for (int k = 0; k < 32; ++k) a2 += bv[k] * Wout[k * 32 + t];
            bvw[t] = a2;
        }
    }
}

// ---- main kernel: 8 lanes/query-slot, 2 queries per thread (16 q/wave).
// lane owns channels 4l..4l+3. Plane as uint4*: plane stride 1<<17, y stride
// 1<<10, x stride 1<<3; lane adds +l. One uint4 = 4 ch x {x0,x1} fp16.

struct f4 { v2f lo, hi; };   // 4 channels

// one sample in flight: 6 row-loads + 4 interpolation fracs (28 VGPRs)
struct Samp { uint4 u[6]; float wc0, wc1, wr1, wr2; };

__device__ __forceinline__ Samp load_samp(const uint4* __restrict__ P0,
                                          float p0, float p1, float p2) {
    Samp t;
    float x0c = fminf(fmaxf(p0, 0.f), 1.f) * 127.f;
    float x1c = fminf(fmaxf(p1, 0.f), 1.f) * 127.f;
    float x2c = fminf(fmaxf(p2, 0.f), 1.f) * 127.f;
    int i0 = min((int)x0c, 126);
    t.wc0 = x0c - (float)i0;
    int i1 = min((int)x1c, 126);
    t.wc1 = x1c - (float)i1;
    float f1 = floorf(x1c);
    int r10 = (int)f1, r11 = min(r10 + 1, 127);
    t.wr1 = x1c - f1;
    float f2 = floorf(x2c);
    int r20 = (int)f2, r21 = min(r20 + 1, 127);
    t.wr2 = x2c - f2;

    const uint4* Pxz = P0;
    const uint4* Pxy = P0 + (1 << 17);
    const uint4* Pyz = P0 + (2 << 17);
    int c0 = i0 << 3, c1 = i1 << 3;
    int R10 = r10 << 10, R11 = r11 << 10;
    int R20 = r20 << 10, R21 = r21 << 10;
    t.u[0] = Pxz[R20 + c0];  t.u[1] = Pxz[R21 + c0];
    t.u[2] = Pxy[R10 + c0];  t.u[3] = Pxy[R11 + c0];
    t.u[4] = Pyz[R20 + c1];  t.u[5] = Pyz[R21 + c1];
    return t;
}

#if HAVE_DOT2
__device__ __forceinline__ void eval_row(f4& acc, uint4 u, h2 w) {
    acc.lo.x = __builtin_amdgcn_fdot2(__builtin_bit_cast(h2, u.x), w, acc.lo.x, false);
    acc.lo.y = __builtin_amdgcn_fdot2(__builtin_bit_cast(h2, u.y), w, acc.lo.y, false);
    acc.hi.x = __builtin_amdgcn_fdot2(__builtin_bit_cast(h2, u.z), w, acc.hi.x, false);
    acc.hi.y = __builtin_amdgcn_fdot2(__builtin_bit_cast(h2, u.w), w, acc.hi.y, false);
}

__device__ __forceinline__ void eval_plane(f4& acc, uint4 ua, uint4 ub,
                                           float wx, float wy) {
    float wB1 = wx * wy;          // (x1,y1)
    float wB0 = wx - wB1;         // (x1,y0)
    float wA1 = wy - wB1;         // (x0,y1)
    float wA0 = 1.f - wx - wA1;   // (x0,y0)
    h2 w0 = __builtin_bit_cast(h2, __builtin_amdgcn_cvt_pkrtz(wA0, wB0));
    h2 w1 = __builtin_bit_cast(h2, __builtin_amdgcn_cvt_pkrtz(wA1, wB1));
    eval_row(acc, ua, w0);
    eval_row(acc, ub, w1);
}
#else
__device__ __forceinline__ void eval_row(f4& acc, uint4 u, float wA, float wB) {
    __half2 h0 = __builtin_bit_cast(__half2, u.x);
    __half2 h1 = __builtin_bit_cast(__half2, u.y);
    __half2 h2_ = __builtin_bit_cast(__half2, u.z);
    __half2 h3 = __builtin_bit_cast(__half2, u.w);
    acc.lo.x = fmaf(__half2float(h0.y), wB, fmaf(__half2float(h0.x), wA, acc.lo.x));
    acc.lo.y = fmaf(__half2float(h1.y), wB, fmaf(__half2float(h1.x), wA, acc.lo.y));
    acc.hi.x = fmaf(__half2float(h2_.y), wB, fmaf(__half2float(h2_.x), wA, acc.hi.x));
    acc.hi.y = fmaf(__half2float(h3.y), wB, fmaf(__half2float(h3.x), wA, acc.hi.y));
}

__device__ __forceinline__ void eval_plane(f4& acc, uint4 ua, uint4 ub,
                                           float wx, float wy) {
    float wB1 = wx * wy;
    float wB0 = wx - wB1;
    float wA1 = wy - wB1;
    float wA0 = 1.f - wx - wA1;
    eval_row(acc, ua, wA0, wB0);
    eval_row(acc, ub, wA1, wB1);
}
#endif

__device__ __forceinline__ void eval_samp(const Samp& t, f4& acc) {
    eval_plane(acc, t.u[0], t.u[1], t.wc0, t.wr2);   // XZ
    eval_plane(acc, t.u[2], t.u[3], t.wc0, t.wr1);   // XY
    eval_plane(acc, t.u[4], t.u[5], t.wc1, t.wr2);   // YZ
}

// element idx (0..3 within lane) of f4; compile-time idx.
#define GETE(v, idx) (((idx) & 2) ? (((idx) & 1) ? (v).hi.y : (v).hi.x) \
                                  : (((idx) & 1) ? (v).lo.y : (v).lo.x))
// broadcast channel idx (0..31) across the 8-lane query group (base = tid & 56).
#define GETC(v, idx) __shfl(GETE(v, idx), base | ((idx) >> 2), 64)

__global__ __launch_bounds__(256)
void eda_main(const float* __restrict__ qp, const unsigned* __restrict__ tp,
              const float* __restrict__ Woff, const float* __restrict__ boff,
              const float* __restrict__ Ww, const float* __restrict__ bw,
              const float* __restrict__ Wc, const float* __restrict__ bvw,
              const float* __restrict__ bout, float* __restrict__ out) {
    __shared__ float sWcat[32][32];   // [k][j]: j<24 -> W_off, else W_w
    __shared__ float sWc2[32][32];    // [k][j]: W_v@W_out
    __shared__ float sbcat[32];
    __shared__ float sbvw[32];
    __shared__ float sbout[32];

    int tid = threadIdx.x;
    int lane = tid & 7;
    int base = tid & 56;                           // query-group base within wave
    int b  = blockIdx.x & 1;                       // XCD-parity batch split
    int q0 = (blockIdx.x >> 1) * 64 + (tid >> 3);  // this thread's first query
    int q1 = q0 + 32;                              // second query
    int qq0 = min(q0, NS - 1);
    int qq1 = min(q1, NS - 1);

    const float* pA = qp + ((size_t)b * NS + qq0) * 3;
    const float* pB = qp + ((size_t)b * NS + qq1) * 3;
    float a0 = pA[0], a1 = pA[1], a2 = pA[2];
    float b0 = pB[0], b1 = pB[1], b2 = pB[2];

    const uint4* P0 = (const uint4*)tp + (((size_t)(b * 3)) << 17) + lane;

    // ---- issue both feature samples' loads early; fly during LDS staging ----
    Samp fsA = load_samp(P0, a0, a1, a2);
    Samp fsB = load_samp(P0, b0, b1, b2);

    for (int i = tid; i < 1024; i += 256) {
        int k = i >> 5, j = i & 31;
        ((float*)sWcat)[i] = (j < 24) ? Woff[k * 24 + j] : Ww[k * 8 + (j - 24)];
        ((float*)sWc2)[i]  = Wc[i];
    }
    if (tid < 32) {
        sbcat[tid] = (tid < 24) ? boff[tid] : bw[tid - 24];
        sbvw[tid]  = bvw[tid];
        sbout[tid] = bout[tid];
    }
    __syncthreads();

    // ---- features ----
    f4 featA; featA.lo = (v2f){0.f, 0.f}; featA.hi = (v2f){0.f, 0.f};
    f4 featB; featB.lo = (v2f){0.f, 0.f}; featB.hi = (v2f){0.f, 0.f};
    eval_samp(fsA, featA);
    eval_samp(fsB, featB);

    // ---- cat = feature @ [W_off | W_w] + bias (weights read once, used twice) ----
    f4 catA, catB;
    catA.lo.x = sbcat[(lane << 2) + 0]; catA.lo.y = sbcat[(lane << 2) + 1];
    catA.hi.x = sbcat[(lane << 2) + 2]; catA.hi.y = sbcat[(lane << 2) + 3];
    catB = catA;
#pragma unroll
    for (int k = 0; k < 32; ++k) {
        float fA = GETC(featA, k);
        float fB = GETC(featB, k);
        const v2f* wp = (const v2f*)&sWcat[k][lane << 2];
        v2f w0 = wp[0], w1 = wp[1];
        v2f fA2 = {fA, fA}, fB2 = {fB, fB};
        catA.lo = __builtin_elementwise_fma(fA2, w0, catA.lo);
        catA.hi = __builtin_elementwise_fma(fA2, w1, catA.hi);
        catB.lo = __builtin_elementwise_fma(fB2, w0, catB.lo);
        catB.hi = __builtin_elementwise_fma(fB2, w1, catB.hi);
    }

    // ---- s-loop: two independent queries interleaved, depth-1 prefetch ----
    f4 waA; waA.lo = (v2f){0.f, 0.f}; waA.hi = (v2f){0.f, 0.f};
    f4 waB; waB.lo = (v2f){0.f, 0.f}; waB.hi = (v2f){0.f, 0.f};
    float wsumA = 0.f, wsumB = 0.f;
    Samp curA = load_samp(P0, a0 + GETC(catA, 0), a1 + GETC(catA, 1), a2 + GETC(catA, 2));
    Samp curB = load_samp(P0, b0 + GETC(catB, 0), b1 + GETC(catB, 1), b2 + GETC(catB, 2));
    Samp nxtA, nxtB;
#pragma unroll
    for (int s = 0; s < SS; ++s) {
        if (s < SS - 1) {
            nxtA = load_samp(P0, a0 + GETC(catA, 3 * (s + 1) + 0),
                                 a1 + GETC(catA, 3 * (s + 1) + 1),
                                 a2 + GETC(catA, 3 * (s + 1) + 2));
            nxtB = load_samp(P0, b0 + GETC(catB, 3 * (s + 1) + 0),
                                 b1 + GETC(catB, 3 * (s + 1) + 1),
                                 b2 + GETC(catB, 3 * (s + 1) + 2));
        }
        f4 auxA; auxA.lo = (v2f){0.f, 0.f}; auxA.hi = (v2f){0.f, 0.f};
        f4 auxB; auxB.lo = (v2f){0.f, 0.f}; auxB.hi = (v2f){0.f, 0.f};
        eval_samp(curA, auxA);
        eval_samp(curB, auxB);
        float wA = GETC(catA, 24 + s);
        float wB = GETC(catB, 24 + s);
        v2f wA2 = {wA, wA}, wB2 = {wB, wB};
        waA.lo = __builtin_elementwise_fma(wA2, auxA.lo, waA.lo);
        waA.hi = __builtin_elementwise_fma(wA2, auxA.hi, waA.hi);
        waB.lo = __builtin_elementwise_fma(wB2, auxB.lo, waB.lo);
        waB.hi = __builtin_elementwise_fma(wB2, auxB.hi, waB.hi);
        wsumA += wA;
        wsumB += wB;
        if (s < SS - 1) { curA = nxtA; curB = nxtB; }
    }

    // ---- out = wa @ (W_v@W_out) + wsum*(b_v@W_out) + b_out + feature ----
    f4 oA, oB;
    {
        v2f bo0 = {sbout[(lane << 2) + 0], sbout[(lane << 2) + 1]};
        v2f bo1 = {sbout[(lane << 2) + 2], sbout[(lane << 2) + 3]};
        v2f bv0 = {sbvw[(lane << 2) + 0], sbvw[(lane << 2) + 1]};
        v2f bv1 = {sbvw[(lane << 2) + 2], sbvw[(lane << 2) + 3]};
        v2f wsA = {wsumA, wsumA}, wsB = {wsumB, wsumB};
        oA.lo = __builtin_elementwise_fma(wsA, bv0, bo0) + featA.lo;
        oA.hi = __builtin_elementwise_fma(wsA, bv1, bo1) + featA.hi;
        oB.lo = __builtin_elementwise_fma(wsB, bv0, bo0) + featB.lo;
        oB.hi = __builtin_elementwise_fma(wsB, bv1, bo1) + featB.hi;
    }
#pragma unroll
    for (int k = 0; k < 32; ++k) {
        float wA = GETC(waA, k);
        float wB = GETC(waB, k);
        const v2f* wp = (const v2f*)&sWc2[k][lane << 2];
        v2f w0 = wp[0], w1 = wp[1];
        v2f wA2 = {wA, wA}, wB2 = {wB, wB};
        oA.lo = __builtin_elementwise_fma(wA2, w0, oA.lo);
        oA.hi = __builtin_elementwise_fma(wA2, w1, oA.hi);
        oB.lo = __builtin_elementwise_fma(wB2, w0, oB.lo);
        oB.hi = __builtin_elementwise_fma(wB2, w1, oB.hi);
    }

    if (q0 < NS) {
        float* dst = out + ((size_t)b * NS + q0) * 32 + (lane << 2);
        *(float4*)dst = make_float4(oA.lo.x, oA.lo.y, oA.hi.x, oA.hi.y);
    }
    if (q1 < NS) {
        float* dst = out + ((size_t)b * NS + q1) * 32 + (lane << 2);
        *(float4*)dst = make_float4(oB.lo.x, oB.lo.y, oB.hi.x, oB.hi.y);
    }
}

extern "C" void kernel_launch(void* const* d_in, const int* in_sizes, int n_in,
                              void* d_out, int out_size, void* d_ws, size_t ws_size,
                              hipStream_t stream) {
    const float* qp   = (const float*)d_in[0];
    const float* cxz  = (const float*)d_in[1];
    const float* cxy  = (const float*)d_in[2];
    const float* cyz  = (const float*)d_in[3];
    const float* Woff = (const float*)d_in[4];
    const float* boff = (const float*)d_in[5];
    const float* Ww   = (const float*)d_in[6];
    const float* bw   = (const float*)d_in[7];
    const float* Wv   = (const float*)d_in[8];
    const float* bv   = (const float*)d_in[9];
    const float* Wout = (const float*)d_in[10];
    const float* bout = (const float*)d_in[11];
    float* out = (float*)d_out;

    unsigned* tp = (unsigned*)d_ws;
    float* Wc  = (float*)((char*)d_ws + (size_t)BS * 3 * RR * RR * CCH * 4);
    float* bvw = Wc + 1024;

    prep<<<BS * 3 * RR + 4, 256, 0, stream>>>(cxz, cxy, cyz, Wv, bv, Wout, tp, Wc, bvw);
    // even blockIdx -> batch 0, odd -> batch 1 (round-robin block->XCD dispatch
    // biases each XCD toward one batch's 6.3 MB replicated planes).
    int blocks_per_batch = (NS + 63) / 64;   // 64 queries per 256-thread block
    eda_main<<<2 * blocks_per_batch, 256, 0, stream>>>(qp, tp, Woff, boff, Ww, bw,
                                                       Wc, bvw, bout, out);
}

// Round 16
// 131.455 us; speedup vs baseline: 1.2917x; 1.2917x over previous
//
#include <hip/hip_runtime.h>
#include <hip/hip_fp16.h>

#define BS 2
#define NS 50000
#define CCH 32
#define RR 128
#define SS 8

typedef float v2f __attribute__((ext_vector_type(2)));
typedef _Float16 h2 __attribute__((ext_vector_type(2)));

#if __has_builtin(__builtin_amdgcn_fdot2)
#define HAVE_DOT2 1
#else
#define HAVE_DOT2 0
#endif

// ws layout:
//   tp : BS*3*RR*RR blocks of 128 B (pair-replicated fp16 planes):
//        block (b,pl,y,x) holds channels c=0..31 interleaved {col x, col x+1}:
//        uint32 #c = half(src[c][y][x]) | half(src[c][y][min(x+1,127)])<<16
//        = 12,582,912 B
//   Wc : 1024 floats  (W_v @ W_out)
//   bvw: 32 floats    (b_v @ W_out)

// blocks 0..767: transpose+convert+replicate one (b,pl,y) row via LDS.
// blocks 768..771: compute Wc = Wv@Wout and bvw = bv@Wout.
__global__ __launch_bounds__(256)
void prep(const float* __restrict__ cxz,
          const float* __restrict__ cxy,
          const float* __restrict__ cyz,
          const float* __restrict__ Wv, const float* __restrict__ bv,
          const float* __restrict__ Wout,
          unsigned* __restrict__ tp, float* __restrict__ Wc,
          float* __restrict__ bvw) {
    __shared__ float lds[32 * 129];
    int tid = threadIdx.x;
    int row = blockIdx.x;
    if (row < BS * 3 * RR) {
        int y  = row & 127;
        int pl = (row >> 7) % 3;
        int b  = row / 384;
        const float* src = (pl == 0) ? cxz : ((pl == 1) ? cxy : cyz);
        const float* sp = src + (((size_t)(b * CCH)) << 14) + (y << 7);
#pragma unroll
        for (int i = 0; i < 16; ++i) {
            int c = (tid >> 7) + 2 * i;
            int x = tid & 127;
            lds[c * 129 + x] = sp[((size_t)c << 14) + x];
        }
        __syncthreads();
        unsigned* dst = tp + ((size_t)row << 12);   // 128 x * 32 c uints per row
#pragma unroll
        for (int i = 0; i < 16; ++i) {
            int idx = tid + 256 * i;                // 0..4095
            int c = idx & 31;
            int x = idx >> 5;
            int x1 = min(x + 1, 127);
            unsigned h0 = __half_as_ushort(__float2half(lds[c * 129 + x]));
            unsigned h1 = __half_as_ushort(__float2half(lds[c * 129 + x1]));
            dst[(x << 5) + c] = h0 | (h1 << 16);
        }
    } else {
        int t = (row - BS * 3 * RR) * 256 + tid;    // 0..1023
        int c = t >> 5, j = t & 31;
        float acc = 0.f;
#pragma unroll
        for (int k = 0; k < 32; ++k) acc += Wv[c * 32 + k] * Wout[k * 32 + j];
        Wc[t] = acc;
        if (t < 32) {
            float a2 = 0.f;
#pragma unroll
            for (int k = 0; k < 32; ++k) a2 += bv[k] * Wout[k * 32 + t];
            bvw[t] = a2;
        }
    }
}

// ---- main kernel: 8 lanes/query (8 queries/wave), lane owns channels 4l..4l+3.
// Plane as uint4*: plane stride 1<<17, y stride 1<<10, x stride 1<<3; lane adds +l.
// One uint4 = lane's 4 channels x {x0, x1} (fp16 interleaved).

struct f4 { v2f lo, hi; };   // 4 channels

// one sample in flight: 6 row-loads + 4 interpolation fracs
struct Samp { uint4 u[6]; float wc0, wc1, wr1, wr2; };

__device__ __forceinline__ Samp load_samp(const uint4* __restrict__ P0,
                                          float p0, float p1, float p2) {
    Samp t;
    float x0c = fminf(fmaxf(p0, 0.f), 1.f) * 127.f;
    float x1c = fminf(fmaxf(p1, 0.f), 1.f) * 127.f;
    float x2c = fminf(fmaxf(p2, 0.f), 1.f) * 127.f;
    int i0 = min((int)x0c, 126);
    t.wc0 = x0c - (float)i0;
    int i1 = min((int)x1c, 126);
    t.wc1 = x1c - (float)i1;
    float f1 = floorf(x1c);
    int r10 = (int)f1, r11 = min(r10 + 1, 127);
    t.wr1 = x1c - f1;
    float f2 = floorf(x2c);
    int r20 = (int)f2, r21 = min(r20 + 1, 127);
    t.wr2 = x2c - f2;

    const uint4* Pxz = P0;
    const uint4* Pxy = P0 + (1 << 17);
    const uint4* Pyz = P0 + (2 << 17);
    int c0 = i0 << 3, c1 = i1 << 3;
    int R10 = r10 << 10, R11 = r11 << 10;
    int R20 = r20 << 10, R21 = r21 << 10;
    t.u[0] = Pxz[R20 + c0];  t.u[1] = Pxz[R21 + c0];
    t.u[2] = Pxy[R10 + c0];  t.u[3] = Pxy[R11 + c0];
    t.u[4] = Pyz[R20 + c1];  t.u[5] = Pyz[R21 + c1];
    return t;
}

#if HAVE_DOT2
__device__ __forceinline__ void eval_row(f4& acc, uint4 u, h2 w) {
    acc.lo.x = __builtin_amdgcn_fdot2(__builtin_bit_cast(h2, u.x), w, acc.lo.x, false);
    acc.lo.y = __builtin_amdgcn_fdot2(__builtin_bit_cast(h2, u.y), w, acc.lo.y, false);
    acc.hi.x = __builtin_amdgcn_fdot2(__builtin_bit_cast(h2, u.z), w, acc.hi.x, false);
    acc.hi.y = __builtin_amdgcn_fdot2(__builtin_bit_cast(h2, u.w), w, acc.hi.y, false);
}

__device__ __forceinline__ void eval_plane(f4& acc, uint4 ua, uint4 ub,
                                           float wx, float wy) {
    float wB1 = wx * wy;          // (x1,y1)
    float wB0 = wx - wB1;         // (x1,y0)
    float wA1 = wy - wB1;         // (x0,y1)
    float wA0 = 1.f - wx - wA1;   // (x0,y0)
    h2 w0 = __builtin_bit_cast(h2, __builtin_amdgcn_cvt_pkrtz(wA0, wB0));
    h2 w1 = __builtin_bit_cast(h2, __builtin_amdgcn_cvt_pkrtz(wA1, wB1));
    eval_row(acc, ua, w0);
    eval_row(acc, ub, w1);
}
#else
__device__ __forceinline__ void eval_row(f4& acc, uint4 u, float wA, float wB) {
    __half2 h0 = __builtin_bit_cast(__half2, u.x);
    __half2 h1 = __builtin_bit_cast(__half2, u.y);
    __half2 h2_ = __builtin_bit_cast(__half2, u.z);
    __half2 h3 = __builtin_bit_cast(__half2, u.w);
    acc.lo.x = fmaf(__half2float(h0.y), wB, fmaf(__half2float(h0.x), wA, acc.lo.x));
    acc.lo.y = fmaf(__half2float(h1.y), wB, fmaf(__half2float(h1.x), wA, acc.lo.y));
    acc.hi.x = fmaf(__half2float(h2_.y), wB, fmaf(__half2float(h2_.x), wA, acc.hi.x));
    acc.hi.y = fmaf(__half2float(h3.y), wB, fmaf(__half2float(h3.x), wA, acc.hi.y));
}

__device__ __forceinline__ void eval_plane(f4& acc, uint4 ua, uint4 ub,
                                           float wx, float wy) {
    float wB1 = wx * wy;
    float wB0 = wx - wB1;
    float wA1 = wy - wB1;
    float wA0 = 1.f - wx - wA1;
    eval_row(acc, ua, wA0, wB0);
    eval_row(acc, ub, wA1, wB1);
}
#endif

__device__ __forceinline__ void eval_samp(const Samp& t, f4& acc) {
    eval_plane(acc, t.u[0], t.u[1], t.wc0, t.wr2);   // XZ
    eval_plane(acc, t.u[2], t.u[3], t.wc0, t.wr1);   // XY
    eval_plane(acc, t.u[4], t.u[5], t.wc1, t.wr2);   // YZ
}

// element idx (0..3 within lane) of f4; compile-time idx.
#define GETE(v, idx) (((idx) & 2) ? (((idx) & 1) ? (v).hi.y : (v).hi.x) \
                                  : (((idx) & 1) ? (v).lo.y : (v).lo.x))
// broadcast channel idx (0..31) across the 8-lane query group (base = tid & 56).
#define GETC(v, idx) __shfl(GETE(v, idx), base | ((idx) >> 2), 64)

__global__ __launch_bounds__(256)
void eda_main(const float* __restrict__ qp, const unsigned* __restrict__ tp,
              const float* __restrict__ Woff, const float* __restrict__ boff,
              const float* __restrict__ Ww, const float* __restrict__ bw,
              const float* __restrict__ Wc, const float* __restrict__ bvw,
              const float* __restrict__ bout, float* __restrict__ out) {
    __shared__ float sWcat[32][32];   // [k][j]: j<24 -> W_off, else W_w
    __shared__ float sWc2[32][32];    // [k][j]: W_v@W_out
    __shared__ float sbcat[32];
    __shared__ float sbvw[32];
    __shared__ float sbout[32];

    int tid = threadIdx.x;
    int lane = tid & 7;
    int base = tid & 56;                          // query-group base within wave
    int b  = blockIdx.x & 1;                      // XCD-parity batch split
    int qi = (blockIdx.x >> 1) * 32 + (tid >> 3); // query within batch
    int qq = min(qi, NS - 1);

    const float* p = qp + ((size_t)b * NS + qq) * 3;
    float p0 = p[0], p1 = p[1], p2 = p[2];

    const uint4* P0 = (const uint4*)tp + (((size_t)(b * 3)) << 17) + lane;

    // ---- issue feature tap loads early; they fly during LDS weight staging ----
    Samp fs = load_samp(P0, p0, p1, p2);

    for (int i = tid; i < 1024; i += 256) {
        int k = i >> 5, j = i & 31;
        ((float*)sWcat)[i] = (j < 24) ? Woff[k * 24 + j] : Ww[k * 8 + (j - 24)];
        ((float*)sWc2)[i]  = Wc[i];
    }
    if (tid < 32) {
        sbcat[tid] = (tid < 24) ? boff[tid] : bw[tid - 24];
        sbvw[tid]  = bvw[tid];
        sbout[tid] = bout[tid];
    }
    __syncthreads();

    // ---- feature ----
    f4 feat; feat.lo = (v2f){0.f, 0.f}; feat.hi = (v2f){0.f, 0.f};
    eval_samp(fs, feat);

    // ---- cat = feature @ [W_off | W_w] + bias ----
    f4 cat;
    cat.lo.x = sbcat[(lane << 2) + 0]; cat.lo.y = sbcat[(lane << 2) + 1];
    cat.hi.x = sbcat[(lane << 2) + 2]; cat.hi.y = sbcat[(lane << 2) + 3];
#pragma unroll
    for (int k = 0; k < 32; ++k) {
        float fc = GETC(feat, k);
        const v2f* wp = (const v2f*)&sWcat[k][lane << 2];
        v2f fc2 = {fc, fc};
        cat.lo = __builtin_elementwise_fma(fc2, wp[0], cat.lo);
        cat.hi = __builtin_elementwise_fma(fc2, wp[1], cat.hi);
    }

    // ---- software-pipelined s-loop: prefetch s+1's 6 loads during s's eval ----
    f4 wa; wa.lo = (v2f){0.f, 0.f}; wa.hi = (v2f){0.f, 0.f};
    float wsum = 0.f;
    float w_cur = GETC(cat, 24);
    Samp cur = load_samp(P0, p0 + GETC(cat, 0), p1 + GETC(cat, 1), p2 + GETC(cat, 2));
    Samp nxt;
    float w_nxt;
#pragma unroll
    for (int s = 0; s < SS; ++s) {
        if (s < SS - 1) {
            w_nxt = GETC(cat, 24 + (s + 1));
            nxt = load_samp(P0, p0 + GETC(cat, 3 * (s + 1) + 0),
                                p1 + GETC(cat, 3 * (s + 1) + 1),
                                p2 + GETC(cat, 3 * (s + 1) + 2));
        }
        f4 aux; aux.lo = (v2f){0.f, 0.f}; aux.hi = (v2f){0.f, 0.f};
        eval_samp(cur, aux);
        v2f w2 = {w_cur, w_cur};
        wa.lo = __builtin_elementwise_fma(w2, aux.lo, wa.lo);
        wa.hi = __builtin_elementwise_fma(w2, aux.hi, wa.hi);
        wsum += w_cur;
        if (s < SS - 1) { cur = nxt; w_cur = w_nxt; }
    }

    // ---- out = wa @ (W_v@W_out) + wsum*(b_v@W_out) + b_out + feature ----
    f4 o;
    v2f ws2 = {wsum, wsum};
    {
        v2f bo  = {sbout[(lane << 2) + 0], sbout[(lane << 2) + 1]};
        v2f bv2 = {sbvw[(lane << 2) + 0], sbvw[(lane << 2) + 1]};
        o.lo = __builtin_elementwise_fma(ws2, bv2, bo) + feat.lo;
        v2f bo2 = {sbout[(lane << 2) + 2], sbout[(lane << 2) + 3]};
        v2f bv3 = {sbvw[(lane << 2) + 2], sbvw[(lane << 2) + 3]};
        o.hi = __builtin_elementwise_fma(ws2, bv3, bo2) + feat.hi;
    }
#pragma unroll
    for (int k = 0; k < 32; ++k) {
        float wc = GETC(wa, k);
        const v2f* wp = (const v2f*)&sWc2[k][lane << 2];
        v2f wc2 = {wc, wc};
        o.lo = __builtin_elementwise_fma(wc2, wp[0], o.lo);
        o.hi = __builtin_elementwise_fma(wc2, wp[1], o.hi);
    }

    if (qi < NS) {
        float* dst = out + ((size_t)b * NS + qi) * 32 + (lane << 2);
        *(float4*)dst = make_float4(o.lo.x, o.lo.y, o.hi.x, o.hi.y);
    }
}

extern "C" void kernel_launch(void* const* d_in, const int* in_sizes, int n_in,
                              void* d_out, int out_size, void* d_ws, size_t ws_size,
                              hipStream_t stream) {
    const float* qp   = (const float*)d_in[0];
    const float* cxz  = (const float*)d_in[1];
    const float* cxy  = (const float*)d_in[2];
    const float* cyz  = (const float*)d_in[3];
    const float* Woff = (const float*)d_in[4];
    const float* boff = (const float*)d_in[5];
    const float* Ww   = (const float*)d_in[6];
    const float* bw   = (const float*)d_in[7];
    const float* Wv   = (const float*)d_in[8];
    const float* bv   = (const float*)d_in[9];
    const float* Wout = (const float*)d_in[10];
    const float* bout = (const float*)d_in[11];
    float* out = (float*)d_out;

    unsigned* tp = (unsigned*)d_ws;
    float* Wc  = (float*)((char*)d_ws + (size_t)BS * 3 * RR * RR * CCH * 4);
    float* bvw = Wc + 1024;

    prep<<<BS * 3 * RR + 4, 256, 0, stream>>>(cxz, cxy, cyz, Wv, bv, Wout, tp, Wc, bvw);
    // even blockIdx -> batch 0, odd -> batch 1 (round-robin block->XCD dispatch
    // biases each XCD toward one batch's 6.3 MB replicated planes).
    int blocks_per_batch = (NS + 31) / 32;   // 32 queries per 256-thread block
    eda_main<<<2 * blocks_per_batch, 256, 0, stream>>>(qp, tp, Woff, boff, Ww, bw,
                                                       Wc, bvw, bout, out);
}